// Round 1
// baseline (987.459 us; speedup 1.0000x reference)
//
#include <hip/hip_runtime.h>

// GraphSAGE 2-layer: logits = meanAgg(relu(meanAgg(x@W1)) @ W2)
// N=100000, E=1600000, D_IN=128, D_H=128, D_OUT=64, all fp32.
//
// Pipeline per call (all on `stream`, graph-capture safe):
//   1. memset deg=0; histogram deg[row[e]]++        (atomics, 1.6M)
//   2. single-block scan -> offsets, cursor, invdeg
//   3. scatter edges into CSR (csr[pos]=col)
//   4. gemm1: h1 = x @ W1                           (LDS-tiled fp32)
//   5. agg1:  h  = relu(gather-mean(h1))            (1 wave / row, float2 lanes)
//   6. gemm2: h2 = h @ W2                           (h2 aliases h1 buffer)
//   7. agg2:  out = gather-mean(h2)                 (1 wave / row, float lanes)

#define DIN 128
#define DH 128
#define DOUT 64

__global__ __launch_bounds__(256) void k_degree(const int* __restrict__ row,
                                                int* __restrict__ deg, int E) {
    int e = blockIdx.x * blockDim.x + threadIdx.x;
    if (e < E) atomicAdd(&deg[row[e]], 1);
}

// Single-block exclusive scan of deg[0..n) -> offs, cursor; also invdeg = 1/deg.
__global__ __launch_bounds__(1024) void k_scan(const int* __restrict__ deg,
                                               int* __restrict__ offs,
                                               int* __restrict__ cursor,
                                               float* __restrict__ invdeg, int n) {
    __shared__ int sh[1024];
    int t = threadIdx.x;
    int chunk = (n + 1023) / 1024;
    int lo = t * chunk;
    int hi = lo + chunk; if (hi > n) hi = n;
    int s = 0;
    for (int i = lo; i < hi; ++i) s += deg[i];
    sh[t] = s;
    __syncthreads();
    // Hillis-Steele inclusive scan over 1024 partials
    for (int d = 1; d < 1024; d <<= 1) {
        int v = 0;
        if (t >= d) v = sh[t - d];
        __syncthreads();
        if (t >= d) sh[t] += v;
        __syncthreads();
    }
    int run = (t == 0) ? 0 : sh[t - 1];
    for (int i = lo; i < hi; ++i) {
        int d = deg[i];
        offs[i] = run;
        cursor[i] = run;
        invdeg[i] = 1.0f / (float)d;   // every row has >=1 neighbor by construction
        run += d;
    }
}

__global__ __launch_bounds__(256) void k_scatter(const int* __restrict__ row,
                                                 const int* __restrict__ col,
                                                 int* __restrict__ cursor,
                                                 int* __restrict__ csr, int E) {
    int e = blockIdx.x * blockDim.x + threadIdx.x;
    if (e < E) {
        int r = row[e];
        int pos = atomicAdd(&cursor[r], 1);
        csr[pos] = col[e];
    }
}

// h1[n,128] = X[n,128] @ W[128,128]. Block: 64-row x 128-col tile, 256 thr.
__global__ __launch_bounds__(256) void k_gemm1(const float* __restrict__ X,
                                               const float* __restrict__ W,
                                               float* __restrict__ H, int n) {
    __shared__ float ws[128 * 128];     // 64 KB, W fully resident
    __shared__ float xs[64][132];       // pad 128->132 (16B-aligned rows, no conflicts)
    int tid = threadIdx.x;
    int r0 = blockIdx.x * 64;

    for (int i = tid; i < 128 * 128 / 4; i += 256)
        ((float4*)ws)[i] = ((const float4*)W)[i];
    for (int i = tid; i < 64 * 32; i += 256) {
        int r = i >> 5, c4 = i & 31;
        float4 v = make_float4(0.f, 0.f, 0.f, 0.f);
        if (r0 + r < n) v = ((const float4*)X)[(size_t)(r0 + r) * 32 + c4];
        *(float4*)&xs[r][c4 * 4] = v;
    }
    __syncthreads();

    int cg = tid & 31;   // cols 4*cg .. 4*cg+3
    int rg = tid >> 5;   // rows 8*rg .. 8*rg+7
    float acc[8][4];
#pragma unroll
    for (int r = 0; r < 8; ++r)
#pragma unroll
        for (int c = 0; c < 4; ++c) acc[r][c] = 0.f;

    for (int k = 0; k < 128; ++k) {
        float4 w = *(const float4*)&ws[k * 128 + cg * 4];
#pragma unroll
        for (int r = 0; r < 8; ++r) {
            float xv = xs[rg * 8 + r][k];
            acc[r][0] += xv * w.x;
            acc[r][1] += xv * w.y;
            acc[r][2] += xv * w.z;
            acc[r][3] += xv * w.w;
        }
    }
#pragma unroll
    for (int r = 0; r < 8; ++r) {
        int rr = r0 + rg * 8 + r;
        if (rr < n)
            *(float4*)&H[(size_t)rr * 128 + cg * 4] = *(float4*)&acc[r][0];
    }
}

// h2[n,64] = X[n,128] @ W[128,64]. Block: 64-row x 64-col tile, 256 thr.
__global__ __launch_bounds__(256) void k_gemm2(const float* __restrict__ X,
                                               const float* __restrict__ W,
                                               float* __restrict__ H, int n) {
    __shared__ float ws[128 * 64];      // 32 KB
    __shared__ float xs[64][132];
    int tid = threadIdx.x;
    int r0 = blockIdx.x * 64;

    for (int i = tid; i < 128 * 64 / 4; i += 256)
        ((float4*)ws)[i] = ((const float4*)W)[i];
    for (int i = tid; i < 64 * 32; i += 256) {
        int r = i >> 5, c4 = i & 31;
        float4 v = make_float4(0.f, 0.f, 0.f, 0.f);
        if (r0 + r < n) v = ((const float4*)X)[(size_t)(r0 + r) * 32 + c4];
        *(float4*)&xs[r][c4 * 4] = v;
    }
    __syncthreads();

    int cg = tid & 15;   // 16 col groups * 4 cols
    int rg = tid >> 4;   // 16 row groups * 4 rows
    float acc[4][4];
#pragma unroll
    for (int r = 0; r < 4; ++r)
#pragma unroll
        for (int c = 0; c < 4; ++c) acc[r][c] = 0.f;

    for (int k = 0; k < 128; ++k) {
        float4 w = *(const float4*)&ws[k * 64 + cg * 4];
#pragma unroll
        for (int r = 0; r < 4; ++r) {
            float xv = xs[rg * 4 + r][k];
            acc[r][0] += xv * w.x;
            acc[r][1] += xv * w.y;
            acc[r][2] += xv * w.z;
            acc[r][3] += xv * w.w;
        }
    }
#pragma unroll
    for (int r = 0; r < 4; ++r) {
        int rr = r0 + rg * 4 + r;
        if (rr < n)
            *(float4*)&H[(size_t)rr * 64 + cg * 4] = *(float4*)&acc[r][0];
    }
}

// agg1: Hout[row] = relu( (1/deg) * sum_{c in csr[row]} H1[c] ), D=128.
// One wave per row; lane handles float2 -> 512B contiguous per neighbor.
__global__ __launch_bounds__(256) void k_agg1(const float* __restrict__ H1,
                                              const int* __restrict__ offs,
                                              const int* __restrict__ deg,
                                              const float* __restrict__ invdeg,
                                              const int* __restrict__ csr,
                                              float* __restrict__ Hout, int n) {
    int wave = threadIdx.x >> 6, lane = threadIdx.x & 63;
    int row = blockIdx.x * 4 + wave;
    if (row >= n) return;
    int start = offs[row], d = deg[row];
    float a0 = 0.f, a1 = 0.f;
    for (int i = 0; i < d; ++i) {
        int c = csr[start + i];
        float2 v = *(const float2*)&H1[(size_t)c * 128 + lane * 2];
        a0 += v.x;
        a1 += v.y;
    }
    float inv = invdeg[row];
    a0 = fmaxf(a0 * inv, 0.f);
    a1 = fmaxf(a1 * inv, 0.f);
    *(float2*)&Hout[(size_t)row * 128 + lane * 2] = make_float2(a0, a1);
}

// agg2: Out[row] = (1/deg) * sum H2[c], D=64. One wave per row, 1 float/lane.
__global__ __launch_bounds__(256) void k_agg2(const float* __restrict__ H2,
                                              const int* __restrict__ offs,
                                              const int* __restrict__ deg,
                                              const float* __restrict__ invdeg,
                                              const int* __restrict__ csr,
                                              float* __restrict__ Out, int n) {
    int wave = threadIdx.x >> 6, lane = threadIdx.x & 63;
    int row = blockIdx.x * 4 + wave;
    if (row >= n) return;
    int start = offs[row], d = deg[row];
    float a = 0.f;
    for (int i = 0; i < d; ++i) {
        int c = csr[start + i];
        a += H2[(size_t)c * 64 + lane];
    }
    Out[(size_t)row * 64 + lane] = a * invdeg[row];
}

extern "C" void kernel_launch(void* const* d_in, const int* in_sizes, int n_in,
                              void* d_out, int out_size, void* d_ws, size_t ws_size,
                              hipStream_t stream) {
    const float* x    = (const float*)d_in[0];
    const float* W1   = (const float*)d_in[1];
    const float* W2   = (const float*)d_in[2];
    const int*   erow = (const int*)d_in[3];
    const int*   ecol = (const int*)d_in[4];
    const int N = in_sizes[0] / DIN;
    const int E = in_sizes[3];

    size_t o = 0;
    auto take = [&](size_t nbytes) {
        void* p = (char*)d_ws + o;
        o += (nbytes + 255) & ~(size_t)255;
        return p;
    };
    int*   deg    = (int*)take((size_t)N * 4);
    int*   offs   = (int*)take((size_t)N * 4);
    int*   cursor = (int*)take((size_t)N * 4);
    float* invdeg = (float*)take((size_t)N * 4);
    int*   csr    = (int*)take((size_t)E * 4);
    float* h1     = (float*)take((size_t)N * DH * 4);
    float* h      = (float*)take((size_t)N * DH * 4);
    float* h2     = h1;   // gemm2 output reuses h1's buffer (h1 dead after agg1)

    hipMemsetAsync(deg, 0, (size_t)N * 4, stream);
    k_degree<<<(E + 255) / 256, 256, 0, stream>>>(erow, deg, E);
    k_scan<<<1, 1024, 0, stream>>>(deg, offs, cursor, invdeg, N);
    k_scatter<<<(E + 255) / 256, 256, 0, stream>>>(erow, ecol, cursor, csr, E);
    k_gemm1<<<(N + 63) / 64, 256, 0, stream>>>(x, W1, h1, N);
    k_agg1<<<(N + 3) / 4, 256, 0, stream>>>(h1, offs, deg, invdeg, csr, h, N);
    k_gemm2<<<(N + 63) / 64, 256, 0, stream>>>(h, W2, h2, N);
    k_agg2<<<(N + 3) / 4, 256, 0, stream>>>(h2, offs, deg, invdeg, csr, (float*)d_out, N);
}

// Round 2
// 718.506 us; speedup vs baseline: 1.3743x; 1.3743x over previous
//
#include <hip/hip_runtime.h>

// GraphSAGE 2-layer: logits = meanAgg(relu(meanAgg(x@W1)) @ W2)
// N=100000, E=1600000, D_IN=128, D_H=128, D_OUT=64, all fp32.
//
// R2: replaced single-block scan (280us, 0.14% occupancy) with 3-phase
// parallel scan (partials -> scan-partials -> local scan + fixup).

#define DIN 128
#define DH 128
#define DOUT 64

#define SCAN_TPB 256
#define SCAN_EPT 4                      // elements per thread
#define SCAN_CHUNK (SCAN_TPB * SCAN_EPT)  // 1024 elements per block

__global__ __launch_bounds__(256) void k_degree(const int* __restrict__ row,
                                                int* __restrict__ deg, int E) {
    int e = blockIdx.x * blockDim.x + threadIdx.x;
    if (e < E) atomicAdd(&deg[row[e]], 1);
}

// Phase 1: per-block sums of deg.
__global__ __launch_bounds__(SCAN_TPB) void k_scan_part(const int* __restrict__ deg,
                                                        int* __restrict__ bsums, int n) {
    __shared__ int sh[SCAN_TPB];
    int t = threadIdx.x;
    int base = blockIdx.x * SCAN_CHUNK + t * SCAN_EPT;
    int s = 0;
#pragma unroll
    for (int i = 0; i < SCAN_EPT; ++i) {
        int idx = base + i;
        if (idx < n) s += deg[idx];
    }
    sh[t] = s;
    __syncthreads();
    for (int d = SCAN_TPB / 2; d > 0; d >>= 1) {
        if (t < d) sh[t] += sh[t + d];
        __syncthreads();
    }
    if (t == 0) bsums[blockIdx.x] = sh[0];
}

// Phase 2: single small block scans the (<=128) block sums -> exclusive offs.
__global__ __launch_bounds__(128) void k_scan_blk(int* __restrict__ bsums, int nb) {
    __shared__ int sh[128];
    int t = threadIdx.x;
    sh[t] = (t < nb) ? bsums[t] : 0;
    __syncthreads();
    for (int d = 1; d < 128; d <<= 1) {
        int v = (t >= d) ? sh[t - d] : 0;
        __syncthreads();
        sh[t] += v;
        __syncthreads();
    }
    if (t < nb) bsums[t] = (t == 0) ? 0 : sh[t - 1];   // exclusive
}

// Phase 3: per-block local exclusive scan + block offset; emit offs/cursor/invdeg.
__global__ __launch_bounds__(SCAN_TPB) void k_scan_final(const int* __restrict__ deg,
                                                         const int* __restrict__ bsums,
                                                         int* __restrict__ offs,
                                                         int* __restrict__ cursor,
                                                         float* __restrict__ invdeg, int n) {
    __shared__ int sh[SCAN_TPB];
    int t = threadIdx.x;
    int base = blockIdx.x * SCAN_CHUNK + t * SCAN_EPT;
    int d0[SCAN_EPT];
    int s = 0;
#pragma unroll
    for (int i = 0; i < SCAN_EPT; ++i) {
        int idx = base + i;
        d0[i] = (idx < n) ? deg[idx] : 0;
        s += d0[i];
    }
    sh[t] = s;
    __syncthreads();
    for (int d = 1; d < SCAN_TPB; d <<= 1) {
        int v = (t >= d) ? sh[t - d] : 0;
        __syncthreads();
        sh[t] += v;
        __syncthreads();
    }
    int run = bsums[blockIdx.x] + ((t == 0) ? 0 : sh[t - 1]);
#pragma unroll
    for (int i = 0; i < SCAN_EPT; ++i) {
        int idx = base + i;
        if (idx < n) {
            offs[idx] = run;
            cursor[idx] = run;
            invdeg[idx] = 1.0f / (float)d0[i];
            run += d0[i];
        }
    }
}

__global__ __launch_bounds__(256) void k_scatter(const int* __restrict__ row,
                                                 const int* __restrict__ col,
                                                 int* __restrict__ cursor,
                                                 int* __restrict__ csr, int E) {
    int e = blockIdx.x * blockDim.x + threadIdx.x;
    if (e < E) {
        int r = row[e];
        int pos = atomicAdd(&cursor[r], 1);
        csr[pos] = col[e];
    }
}

// h1[n,128] = X[n,128] @ W[128,128]. Block: 64-row x 128-col tile, 256 thr.
__global__ __launch_bounds__(256) void k_gemm1(const float* __restrict__ X,
                                               const float* __restrict__ W,
                                               float* __restrict__ H, int n) {
    __shared__ float ws[128 * 128];
    __shared__ float xs[64][132];
    int tid = threadIdx.x;
    int r0 = blockIdx.x * 64;

    for (int i = tid; i < 128 * 128 / 4; i += 256)
        ((float4*)ws)[i] = ((const float4*)W)[i];
    for (int i = tid; i < 64 * 32; i += 256) {
        int r = i >> 5, c4 = i & 31;
        float4 v = make_float4(0.f, 0.f, 0.f, 0.f);
        if (r0 + r < n) v = ((const float4*)X)[(size_t)(r0 + r) * 32 + c4];
        *(float4*)&xs[r][c4 * 4] = v;
    }
    __syncthreads();

    int cg = tid & 31;
    int rg = tid >> 5;
    float acc[8][4];
#pragma unroll
    for (int r = 0; r < 8; ++r)
#pragma unroll
        for (int c = 0; c < 4; ++c) acc[r][c] = 0.f;

    for (int k = 0; k < 128; ++k) {
        float4 w = *(const float4*)&ws[k * 128 + cg * 4];
#pragma unroll
        for (int r = 0; r < 8; ++r) {
            float xv = xs[rg * 8 + r][k];
            acc[r][0] += xv * w.x;
            acc[r][1] += xv * w.y;
            acc[r][2] += xv * w.z;
            acc[r][3] += xv * w.w;
        }
    }
#pragma unroll
    for (int r = 0; r < 8; ++r) {
        int rr = r0 + rg * 8 + r;
        if (rr < n)
            *(float4*)&H[(size_t)rr * 128 + cg * 4] = *(float4*)&acc[r][0];
    }
}

// h2[n,64] = X[n,128] @ W[128,64]. Block: 64-row x 64-col tile, 256 thr.
__global__ __launch_bounds__(256) void k_gemm2(const float* __restrict__ X,
                                               const float* __restrict__ W,
                                               float* __restrict__ H, int n) {
    __shared__ float ws[128 * 64];
    __shared__ float xs[64][132];
    int tid = threadIdx.x;
    int r0 = blockIdx.x * 64;

    for (int i = tid; i < 128 * 64 / 4; i += 256)
        ((float4*)ws)[i] = ((const float4*)W)[i];
    for (int i = tid; i < 64 * 32; i += 256) {
        int r = i >> 5, c4 = i & 31;
        float4 v = make_float4(0.f, 0.f, 0.f, 0.f);
        if (r0 + r < n) v = ((const float4*)X)[(size_t)(r0 + r) * 32 + c4];
        *(float4*)&xs[r][c4 * 4] = v;
    }
    __syncthreads();

    int cg = tid & 15;
    int rg = tid >> 4;
    float acc[4][4];
#pragma unroll
    for (int r = 0; r < 4; ++r)
#pragma unroll
        for (int c = 0; c < 4; ++c) acc[r][c] = 0.f;

    for (int k = 0; k < 128; ++k) {
        float4 w = *(const float4*)&ws[k * 64 + cg * 4];
#pragma unroll
        for (int r = 0; r < 4; ++r) {
            float xv = xs[rg * 4 + r][k];
            acc[r][0] += xv * w.x;
            acc[r][1] += xv * w.y;
            acc[r][2] += xv * w.z;
            acc[r][3] += xv * w.w;
        }
    }
#pragma unroll
    for (int r = 0; r < 4; ++r) {
        int rr = r0 + rg * 4 + r;
        if (rr < n)
            *(float4*)&H[(size_t)rr * 64 + cg * 4] = *(float4*)&acc[r][0];
    }
}

// agg1: Hout[row] = relu( (1/deg) * sum_{c in csr[row]} H1[c] ), D=128.
__global__ __launch_bounds__(256) void k_agg1(const float* __restrict__ H1,
                                              const int* __restrict__ offs,
                                              const int* __restrict__ deg,
                                              const float* __restrict__ invdeg,
                                              const int* __restrict__ csr,
                                              float* __restrict__ Hout, int n) {
    int wave = threadIdx.x >> 6, lane = threadIdx.x & 63;
    int row = blockIdx.x * 4 + wave;
    if (row >= n) return;
    int start = offs[row], d = deg[row];
    float a0 = 0.f, a1 = 0.f;
    for (int i = 0; i < d; ++i) {
        int c = csr[start + i];
        float2 v = *(const float2*)&H1[(size_t)c * 128 + lane * 2];
        a0 += v.x;
        a1 += v.y;
    }
    float inv = invdeg[row];
    a0 = fmaxf(a0 * inv, 0.f);
    a1 = fmaxf(a1 * inv, 0.f);
    *(float2*)&Hout[(size_t)row * 128 + lane * 2] = make_float2(a0, a1);
}

// agg2: Out[row] = (1/deg) * sum H2[c], D=64.
__global__ __launch_bounds__(256) void k_agg2(const float* __restrict__ H2,
                                              const int* __restrict__ offs,
                                              const int* __restrict__ deg,
                                              const float* __restrict__ invdeg,
                                              const int* __restrict__ csr,
                                              float* __restrict__ Out, int n) {
    int wave = threadIdx.x >> 6, lane = threadIdx.x & 63;
    int row = blockIdx.x * 4 + wave;
    if (row >= n) return;
    int start = offs[row], d = deg[row];
    float a = 0.f;
    for (int i = 0; i < d; ++i) {
        int c = csr[start + i];
        a += H2[(size_t)c * 64 + lane];
    }
    Out[(size_t)row * 64 + lane] = a * invdeg[row];
}

extern "C" void kernel_launch(void* const* d_in, const int* in_sizes, int n_in,
                              void* d_out, int out_size, void* d_ws, size_t ws_size,
                              hipStream_t stream) {
    const float* x    = (const float*)d_in[0];
    const float* W1   = (const float*)d_in[1];
    const float* W2   = (const float*)d_in[2];
    const int*   erow = (const int*)d_in[3];
    const int*   ecol = (const int*)d_in[4];
    const int N = in_sizes[0] / DIN;
    const int E = in_sizes[3];

    size_t o = 0;
    auto take = [&](size_t nbytes) {
        void* p = (char*)d_ws + o;
        o += (nbytes + 255) & ~(size_t)255;
        return p;
    };
    int nscan = (N + SCAN_CHUNK - 1) / SCAN_CHUNK;   // 98 blocks
    int*   deg    = (int*)take((size_t)N * 4);
    int*   offs   = (int*)take((size_t)N * 4);
    int*   cursor = (int*)take((size_t)N * 4);
    float* invdeg = (float*)take((size_t)N * 4);
    int*   bsums  = (int*)take((size_t)nscan * 4);
    int*   csr    = (int*)take((size_t)E * 4);
    float* h1     = (float*)take((size_t)N * DH * 4);
    float* h      = (float*)take((size_t)N * DH * 4);
    float* h2     = h1;   // gemm2 output reuses h1 (dead after agg1)

    hipMemsetAsync(deg, 0, (size_t)N * 4, stream);
    k_degree<<<(E + 255) / 256, 256, 0, stream>>>(erow, deg, E);
    k_scan_part<<<nscan, SCAN_TPB, 0, stream>>>(deg, bsums, N);
    k_scan_blk<<<1, 128, 0, stream>>>(bsums, nscan);
    k_scan_final<<<nscan, SCAN_TPB, 0, stream>>>(deg, bsums, offs, cursor, invdeg, N);
    k_scatter<<<(E + 255) / 256, 256, 0, stream>>>(erow, ecol, cursor, csr, E);
    k_gemm1<<<(N + 63) / 64, 256, 0, stream>>>(x, W1, h1, N);
    k_agg1<<<(N + 3) / 4, 256, 0, stream>>>(h1, offs, deg, invdeg, csr, h, N);
    k_gemm2<<<(N + 63) / 64, 256, 0, stream>>>(h, W2, h2, N);
    k_agg2<<<(N + 3) / 4, 256, 0, stream>>>(h2, offs, deg, invdeg, csr, (float*)d_out, N);
}

// Round 3
// 584.010 us; speedup vs baseline: 1.6908x; 1.2303x over previous
//
#include <hip/hip_runtime.h>

// GraphSAGE 2-layer: logits = meanAgg(relu(meanAgg(x@W1)) @ W2)
// N=100000, E=1600000, D_IN=128, D_H=128, D_OUT=64, all fp32.
//
// R2: 3-phase parallel scan (was 280us single-block -> ~10us).
// R3: agg gather loops unrolled x4 with independent acc chains (4 gathers in
//     flight per wave; was 1 dependent chain -> latency-bound at 2.6TB/s).
//     gemm inner loops k-blocked by 4 with float4 LDS reads (was 8 scalar
//     ds_read_b32 per k).

#define DIN 128
#define DH 128
#define DOUT 64

#define SCAN_TPB 256
#define SCAN_EPT 4
#define SCAN_CHUNK (SCAN_TPB * SCAN_EPT)

__global__ __launch_bounds__(256) void k_degree(const int* __restrict__ row,
                                                int* __restrict__ deg, int E) {
    int e = blockIdx.x * blockDim.x + threadIdx.x;
    if (e < E) atomicAdd(&deg[row[e]], 1);
}

__global__ __launch_bounds__(SCAN_TPB) void k_scan_part(const int* __restrict__ deg,
                                                        int* __restrict__ bsums, int n) {
    __shared__ int sh[SCAN_TPB];
    int t = threadIdx.x;
    int base = blockIdx.x * SCAN_CHUNK + t * SCAN_EPT;
    int s = 0;
#pragma unroll
    for (int i = 0; i < SCAN_EPT; ++i) {
        int idx = base + i;
        if (idx < n) s += deg[idx];
    }
    sh[t] = s;
    __syncthreads();
    for (int d = SCAN_TPB / 2; d > 0; d >>= 1) {
        if (t < d) sh[t] += sh[t + d];
        __syncthreads();
    }
    if (t == 0) bsums[blockIdx.x] = sh[0];
}

__global__ __launch_bounds__(128) void k_scan_blk(int* __restrict__ bsums, int nb) {
    __shared__ int sh[128];
    int t = threadIdx.x;
    sh[t] = (t < nb) ? bsums[t] : 0;
    __syncthreads();
    for (int d = 1; d < 128; d <<= 1) {
        int v = (t >= d) ? sh[t - d] : 0;
        __syncthreads();
        sh[t] += v;
        __syncthreads();
    }
    if (t < nb) bsums[t] = (t == 0) ? 0 : sh[t - 1];
}

__global__ __launch_bounds__(SCAN_TPB) void k_scan_final(const int* __restrict__ deg,
                                                         const int* __restrict__ bsums,
                                                         int* __restrict__ offs,
                                                         int* __restrict__ cursor,
                                                         float* __restrict__ invdeg, int n) {
    __shared__ int sh[SCAN_TPB];
    int t = threadIdx.x;
    int base = blockIdx.x * SCAN_CHUNK + t * SCAN_EPT;
    int d0[SCAN_EPT];
    int s = 0;
#pragma unroll
    for (int i = 0; i < SCAN_EPT; ++i) {
        int idx = base + i;
        d0[i] = (idx < n) ? deg[idx] : 0;
        s += d0[i];
    }
    sh[t] = s;
    __syncthreads();
    for (int d = 1; d < SCAN_TPB; d <<= 1) {
        int v = (t >= d) ? sh[t - d] : 0;
        __syncthreads();
        sh[t] += v;
        __syncthreads();
    }
    int run = bsums[blockIdx.x] + ((t == 0) ? 0 : sh[t - 1]);
#pragma unroll
    for (int i = 0; i < SCAN_EPT; ++i) {
        int idx = base + i;
        if (idx < n) {
            offs[idx] = run;
            cursor[idx] = run;
            invdeg[idx] = 1.0f / (float)d0[i];
            run += d0[i];
        }
    }
}

__global__ __launch_bounds__(256) void k_scatter(const int* __restrict__ row,
                                                 const int* __restrict__ col,
                                                 int* __restrict__ cursor,
                                                 int* __restrict__ csr, int E) {
    int e = blockIdx.x * blockDim.x + threadIdx.x;
    if (e < E) {
        int r = row[e];
        int pos = atomicAdd(&cursor[r], 1);
        csr[pos] = col[e];
    }
}

// h1[n,128] = X[n,128] @ W[128,128]. 64-row x 128-col tile, 256 thr.
__global__ __launch_bounds__(256) void k_gemm1(const float* __restrict__ X,
                                               const float* __restrict__ W,
                                               float* __restrict__ H, int n) {
    __shared__ float ws[128 * 128];
    __shared__ float xs[64][132];       // 132*4=528B row pitch, 16B-aligned
    int tid = threadIdx.x;
    int r0 = blockIdx.x * 64;

    for (int i = tid; i < 128 * 128 / 4; i += 256)
        ((float4*)ws)[i] = ((const float4*)W)[i];
    for (int i = tid; i < 64 * 32; i += 256) {
        int r = i >> 5, c4 = i & 31;
        float4 v = make_float4(0.f, 0.f, 0.f, 0.f);
        if (r0 + r < n) v = ((const float4*)X)[(size_t)(r0 + r) * 32 + c4];
        *(float4*)&xs[r][c4 * 4] = v;
    }
    __syncthreads();

    int cg = tid & 31;
    int rg = tid >> 5;
    float acc[8][4];
#pragma unroll
    for (int r = 0; r < 8; ++r)
#pragma unroll
        for (int c = 0; c < 4; ++c) acc[r][c] = 0.f;

    const float4* ws4 = (const float4*)ws;   // 128 rows x 32 float4
    for (int k4 = 0; k4 < 32; ++k4) {
        float4 w0 = ws4[(k4 * 4 + 0) * 32 + cg];
        float4 w1 = ws4[(k4 * 4 + 1) * 32 + cg];
        float4 w2 = ws4[(k4 * 4 + 2) * 32 + cg];
        float4 w3 = ws4[(k4 * 4 + 3) * 32 + cg];
#pragma unroll
        for (int r = 0; r < 8; ++r) {
            float4 xv = *(const float4*)&xs[rg * 8 + r][k4 * 4];
            acc[r][0] += xv.x * w0.x + xv.y * w1.x + xv.z * w2.x + xv.w * w3.x;
            acc[r][1] += xv.x * w0.y + xv.y * w1.y + xv.z * w2.y + xv.w * w3.y;
            acc[r][2] += xv.x * w0.z + xv.y * w1.z + xv.z * w2.z + xv.w * w3.z;
            acc[r][3] += xv.x * w0.w + xv.y * w1.w + xv.z * w2.w + xv.w * w3.w;
        }
    }
#pragma unroll
    for (int r = 0; r < 8; ++r) {
        int rr = r0 + rg * 8 + r;
        if (rr < n)
            *(float4*)&H[(size_t)rr * 128 + cg * 4] = *(float4*)&acc[r][0];
    }
}

// h2[n,64] = X[n,128] @ W[128,64]. 64-row x 64-col tile, 256 thr.
__global__ __launch_bounds__(256) void k_gemm2(const float* __restrict__ X,
                                               const float* __restrict__ W,
                                               float* __restrict__ H, int n) {
    __shared__ float ws[128 * 64];
    __shared__ float xs[64][132];
    int tid = threadIdx.x;
    int r0 = blockIdx.x * 64;

    for (int i = tid; i < 128 * 64 / 4; i += 256)
        ((float4*)ws)[i] = ((const float4*)W)[i];
    for (int i = tid; i < 64 * 32; i += 256) {
        int r = i >> 5, c4 = i & 31;
        float4 v = make_float4(0.f, 0.f, 0.f, 0.f);
        if (r0 + r < n) v = ((const float4*)X)[(size_t)(r0 + r) * 32 + c4];
        *(float4*)&xs[r][c4 * 4] = v;
    }
    __syncthreads();

    int cg = tid & 15;
    int rg = tid >> 4;
    float acc[4][4];
#pragma unroll
    for (int r = 0; r < 4; ++r)
#pragma unroll
        for (int c = 0; c < 4; ++c) acc[r][c] = 0.f;

    const float4* ws4 = (const float4*)ws;   // 128 rows x 16 float4
    for (int k4 = 0; k4 < 32; ++k4) {
        float4 w0 = ws4[(k4 * 4 + 0) * 16 + cg];
        float4 w1 = ws4[(k4 * 4 + 1) * 16 + cg];
        float4 w2 = ws4[(k4 * 4 + 2) * 16 + cg];
        float4 w3 = ws4[(k4 * 4 + 3) * 16 + cg];
#pragma unroll
        for (int r = 0; r < 4; ++r) {
            float4 xv = *(const float4*)&xs[rg * 4 + r][k4 * 4];
            acc[r][0] += xv.x * w0.x + xv.y * w1.x + xv.z * w2.x + xv.w * w3.x;
            acc[r][1] += xv.x * w0.y + xv.y * w1.y + xv.z * w2.y + xv.w * w3.y;
            acc[r][2] += xv.x * w0.z + xv.y * w1.z + xv.z * w2.z + xv.w * w3.z;
            acc[r][3] += xv.x * w0.w + xv.y * w1.w + xv.z * w2.w + xv.w * w3.w;
        }
    }
#pragma unroll
    for (int r = 0; r < 4; ++r) {
        int rr = r0 + rg * 4 + r;
        if (rr < n)
            *(float4*)&H[(size_t)rr * 64 + cg * 4] = *(float4*)&acc[r][0];
    }
}

// agg1: Hout[row] = relu( (1/deg) * sum_{c in csr[row]} H1[c] ), D=128.
// One wave/row, float2/lane; gather loop unrolled x4, independent acc chains.
__global__ __launch_bounds__(256) void k_agg1(const float* __restrict__ H1,
                                              const int* __restrict__ offs,
                                              const int* __restrict__ deg,
                                              const float* __restrict__ invdeg,
                                              const int* __restrict__ csr,
                                              float* __restrict__ Hout, int n) {
    int wave = threadIdx.x >> 6, lane = threadIdx.x & 63;
    int row = blockIdx.x * 4 + wave;
    if (row >= n) return;
    int start = offs[row], d = deg[row];
    float a0 = 0.f, a1 = 0.f, b0 = 0.f, b1 = 0.f;
    float c0 = 0.f, c1 = 0.f, e0 = 0.f, e1 = 0.f;
    int i = 0;
    for (; i + 4 <= d; i += 4) {
        int n0 = csr[start + i + 0];
        int n1 = csr[start + i + 1];
        int n2 = csr[start + i + 2];
        int n3 = csr[start + i + 3];
        float2 v0 = *(const float2*)&H1[(size_t)n0 * 128 + lane * 2];
        float2 v1 = *(const float2*)&H1[(size_t)n1 * 128 + lane * 2];
        float2 v2 = *(const float2*)&H1[(size_t)n2 * 128 + lane * 2];
        float2 v3 = *(const float2*)&H1[(size_t)n3 * 128 + lane * 2];
        a0 += v0.x; a1 += v0.y;
        b0 += v1.x; b1 += v1.y;
        c0 += v2.x; c1 += v2.y;
        e0 += v3.x; e1 += v3.y;
    }
    for (; i < d; ++i) {
        int c = csr[start + i];
        float2 v = *(const float2*)&H1[(size_t)c * 128 + lane * 2];
        a0 += v.x; a1 += v.y;
    }
    float inv = invdeg[row];
    float r0 = fmaxf((a0 + b0 + c0 + e0) * inv, 0.f);
    float r1 = fmaxf((a1 + b1 + c1 + e1) * inv, 0.f);
    *(float2*)&Hout[(size_t)row * 128 + lane * 2] = make_float2(r0, r1);
}

// agg2: Out[row] = (1/deg) * sum H2[c], D=64. One wave/row, unrolled x4.
__global__ __launch_bounds__(256) void k_agg2(const float* __restrict__ H2,
                                              const int* __restrict__ offs,
                                              const int* __restrict__ deg,
                                              const float* __restrict__ invdeg,
                                              const int* __restrict__ csr,
                                              float* __restrict__ Out, int n) {
    int wave = threadIdx.x >> 6, lane = threadIdx.x & 63;
    int row = blockIdx.x * 4 + wave;
    if (row >= n) return;
    int start = offs[row], d = deg[row];
    float a = 0.f, b = 0.f, c = 0.f, e = 0.f;
    int i = 0;
    for (; i + 4 <= d; i += 4) {
        int n0 = csr[start + i + 0];
        int n1 = csr[start + i + 1];
        int n2 = csr[start + i + 2];
        int n3 = csr[start + i + 3];
        a += H2[(size_t)n0 * 64 + lane];
        b += H2[(size_t)n1 * 64 + lane];
        c += H2[(size_t)n2 * 64 + lane];
        e += H2[(size_t)n3 * 64 + lane];
    }
    for (; i < d; ++i) {
        int n0 = csr[start + i];
        a += H2[(size_t)n0 * 64 + lane];
    }
    Out[(size_t)row * 64 + lane] = (a + b + c + e) * invdeg[row];
}

extern "C" void kernel_launch(void* const* d_in, const int* in_sizes, int n_in,
                              void* d_out, int out_size, void* d_ws, size_t ws_size,
                              hipStream_t stream) {
    const float* x    = (const float*)d_in[0];
    const float* W1   = (const float*)d_in[1];
    const float* W2   = (const float*)d_in[2];
    const int*   erow = (const int*)d_in[3];
    const int*   ecol = (const int*)d_in[4];
    const int N = in_sizes[0] / DIN;
    const int E = in_sizes[3];

    size_t o = 0;
    auto take = [&](size_t nbytes) {
        void* p = (char*)d_ws + o;
        o += (nbytes + 255) & ~(size_t)255;
        return p;
    };
    int nscan = (N + SCAN_CHUNK - 1) / SCAN_CHUNK;
    int*   deg    = (int*)take((size_t)N * 4);
    int*   offs   = (int*)take((size_t)N * 4);
    int*   cursor = (int*)take((size_t)N * 4);
    float* invdeg = (float*)take((size_t)N * 4);
    int*   bsums  = (int*)take((size_t)nscan * 4);
    int*   csr    = (int*)take((size_t)E * 4);
    float* h1     = (float*)take((size_t)N * DH * 4);
    float* h      = (float*)take((size_t)N * DH * 4);
    float* h2     = h1;   // gemm2 output reuses h1 (dead after agg1)

    hipMemsetAsync(deg, 0, (size_t)N * 4, stream);
    k_degree<<<(E + 255) / 256, 256, 0, stream>>>(erow, deg, E);
    k_scan_part<<<nscan, SCAN_TPB, 0, stream>>>(deg, bsums, N);
    k_scan_blk<<<1, 128, 0, stream>>>(bsums, nscan);
    k_scan_final<<<nscan, SCAN_TPB, 0, stream>>>(deg, bsums, offs, cursor, invdeg, N);
    k_scatter<<<(E + 255) / 256, 256, 0, stream>>>(erow, ecol, cursor, csr, E);
    k_gemm1<<<(N + 63) / 64, 256, 0, stream>>>(x, W1, h1, N);
    k_agg1<<<(N + 3) / 4, 256, 0, stream>>>(h1, offs, deg, invdeg, csr, h, N);
    k_gemm2<<<(N + 63) / 64, 256, 0, stream>>>(h, W2, h2, N);
    k_agg2<<<(N + 3) / 4, 256, 0, stream>>>(h2, offs, deg, invdeg, csr, (float*)d_out, N);
}